// Round 18
// baseline (401.629 us; speedup 1.0000x reference)
//
#include <hip/hip_runtime.h>

#define S_LEN 2048
#define NHEAD 32
#define HD 80
#define DPAD 96
#define HIDDEN 2560
#define QKV_N 7680

typedef __attribute__((ext_vector_type(8))) short bf16x8;
typedef __attribute__((ext_vector_type(8))) unsigned short u16x8;
typedef __attribute__((ext_vector_type(4))) float f32x4;

__device__ __forceinline__ unsigned short f2bf(float f) {
  unsigned int u = __float_as_uint(f);
  u += 0x7fffu + ((u >> 16) & 1u);   // RNE
  return (unsigned short)(u >> 16);
}
__device__ __forceinline__ float bf2f(unsigned short h) {
  return __uint_as_float(((unsigned int)h) << 16);
}

__device__ __forceinline__ void gload16(const void* g, void* l) {
  __builtin_amdgcn_global_load_lds((const __attribute__((address_space(1))) void*)g,
                                   (__attribute__((address_space(3))) void*)l, 16, 0, 0);
}

// ---------------- fused prep: fp32->bf16 cvt + both weight transposes -------
__global__ __launch_bounds__(256) void k_prep(const float* __restrict__ hidden,
                                              unsigned short* __restrict__ Abf,
                                              const float* __restrict__ w_qkv,
                                              unsigned short* __restrict__ Wqkvt,
                                              const float* __restrict__ w_dense,
                                              unsigned short* __restrict__ Wdt) {
  __shared__ float tile[64][68];
  const int blk = blockIdx.x;
  if (blk < 10240) {
    int i = blk * 256 + threadIdx.x;
    float4 v = reinterpret_cast<const float4*>(hidden)[i];
    ushort4 o;
    o.x = f2bf(v.x); o.y = f2bf(v.y); o.z = f2bf(v.z); o.w = f2bf(v.w);
    reinterpret_cast<ushort4*>(Abf)[i] = o;
    return;
  }
  const float* in;
  unsigned short* out;
  int R, C, tc, tr;
  if (blk < 15040) {
    int t = blk - 10240;
    in = w_qkv; out = Wqkvt; R = 2560; C = 7680;
    tc = (t % 120) * 64; tr = (t / 120) * 64;
  } else {
    int t = blk - 15040;
    in = w_dense; out = Wdt; R = 2560; C = 2560;
    tc = (t % 40) * 64; tr = (t / 40) * 64;
  }
  for (int i = threadIdx.x; i < 64 * 16; i += 256) {
    int r = i >> 4, c4 = i & 15;
    float4 v = *(const float4*)&in[(size_t)(tr + r) * C + tc + c4 * 4];
    *(float4*)&tile[r][c4 * 4] = v;
  }
  __syncthreads();
  for (int i = threadIdx.x; i < 8 * 64; i += 256) {
    int ro = i >> 6, c = i & 63;
    u16x8 v;
#pragma unroll
    for (int j = 0; j < 8; ++j) v[j] = f2bf(tile[ro * 8 + j][c]);
    *(u16x8*)&out[(size_t)(tc + c) * R + tr + ro * 8] = v;
  }
}

// ---------------- gemm1 (QKV): 256x256, BK=32, R15-exact ---------------------
__global__ __launch_bounds__(512, 2)
void k_gemm_qkv(const unsigned short* __restrict__ A,
                const unsigned short* __restrict__ Bt,
                const float* __restrict__ bias,
                unsigned short* __restrict__ Cbf,
                int M, int N, int K) {
  __shared__ unsigned short sA[4][8192];
  __shared__ unsigned short sB[4][8192];
  const int nbm = M >> 8, nbn = N >> 8;
  const int CM = nbm >> 2, CN = nbn >> 1;
  int wg = blockIdx.x;
  const int xcd = wg & 7;
  const int idx = wg >> 3;
  const int bm = (xcd >> 1) * CM + idx / CN;
  const int bn = (xcd & 1) * CN + idx % CN;
  const int tid = threadIdx.x;
  const int lane = tid & 63, wave = tid >> 6;
  const int wr = wave >> 2, wc = wave & 3;
  const int lc = lane & 15, lr = lane >> 4;

  const int sub = (lane & 7) ^ (lane >> 3);
  const int rstage = wave * 16 + ((lane >> 3) << 1) + (sub >> 2);
  const int cstage = (sub & 3) * 8;
  const unsigned short* Agp = A + (size_t)(bm * 256 + rstage) * K + cstage;
  const unsigned short* Bgp = Bt + (size_t)(bn * 256 + rstage) * K + cstage;
  const size_t halfoff = (size_t)128 * K;

  const int loff = ((lc >> 1) << 7) + (((((lc & 1) << 2) | lr) ^ (lc >> 1)) << 4);

  f32x4 acc[8][4];
  const f32x4 zero = {0.f, 0.f, 0.f, 0.f};
#pragma unroll
  for (int m = 0; m < 8; ++m)
#pragma unroll
    for (int n = 0; n < 4; ++n) acc[m][n] = zero;

  auto stage = [&](int buf, int t) {
    gload16(Agp + t * 32, &sA[buf][wave * 512]);
    gload16(Agp + halfoff + t * 32, &sA[buf][4096 + wave * 512]);
    gload16(Bgp + t * 32, &sB[buf][wave * 512]);
    gload16(Bgp + halfoff + t * 32, &sB[buf][4096 + wave * 512]);
  };

  const int NT = K >> 5;   // 80
#pragma unroll
  for (int t = 0; t < 3; ++t) stage(t, t);

  const int nj = NT >> 2;
  for (int j = 0; j < nj; ++j) {
#pragma unroll
    for (int to = 0; to < 4; ++to) {
      const int t = (j << 2) + to;
      if (t < NT - 2)       asm volatile("s_waitcnt vmcnt(8)" ::: "memory");
      else if (t == NT - 2) asm volatile("s_waitcnt vmcnt(4)" ::: "memory");
      else                  asm volatile("s_waitcnt vmcnt(0)" ::: "memory");
      __builtin_amdgcn_s_barrier();
      asm volatile("" ::: "memory");

      const char* bufA = (const char*)&sA[to][0];
      const char* bufB = (const char*)&sB[to][0];
      bf16x8 af[8], bfr[4];
#pragma unroll
      for (int mi = 0; mi < 8; ++mi)
        af[mi] = *(const bf16x8*)(bufA + ((wr * 128 + mi * 16) << 6) + loff);
#pragma unroll
      for (int ni = 0; ni < 4; ++ni)
        bfr[ni] = *(const bf16x8*)(bufB + ((wc * 64 + ni * 16) << 6) + loff);

      if (t + 3 < NT) stage((to + 3) & 3, t + 3);

      asm volatile("s_waitcnt lgkmcnt(0)" ::: "memory");
      __builtin_amdgcn_sched_barrier(0);
      __builtin_amdgcn_s_setprio(1);
#pragma unroll
      for (int mi = 0; mi < 8; ++mi)
#pragma unroll
        for (int ni = 0; ni < 4; ++ni)
          acc[mi][ni] = __builtin_amdgcn_mfma_f32_16x16x32_bf16(af[mi], bfr[ni], acc[mi][ni], 0, 0, 0);
      __builtin_amdgcn_s_setprio(0);
    }
  }

  __builtin_amdgcn_s_barrier();
  const int rowb = bm * 256 + wr * 128;
  const int colb = bn * 256 + wc * 64;
  unsigned short* myl = (wave < 4) ? &sA[wave][0] : &sB[wave - 4][0];
#pragma unroll
  for (int ni = 0; ni < 4; ++ni) {
    const float bv = bias[colb + ni * 16 + lc];
#pragma unroll
    for (int mf = 0; mf < 8; ++mf)
#pragma unroll
      for (int jj = 0; jj < 4; ++jj)
        myl[(mf * 16 + lr * 4 + jj) * 64 + ni * 16 + lc] = f2bf(acc[mf][ni][jj] + bv);
  }
  asm volatile("" ::: "memory");
#pragma unroll
  for (int i = 0; i < 16; ++i) {
    const int idx2 = i * 64 + lane;
    const int r = idx2 >> 3, c = idx2 & 7;
    *(u16x8*)&Cbf[(size_t)(rowb + r) * N + colb + c * 8] = *(const u16x8*)&myl[r * 64 + c * 8];
  }
}

// ---------------- gemm2 (out-proj): 256x128 tile, 8 waves, 3-deep -----------
__global__ __launch_bounds__(512, 2)
void k_gemm_out(const unsigned short* __restrict__ A,
                const unsigned short* __restrict__ Bt,
                const float* __restrict__ bias,
                float* __restrict__ Cf,
                int M, int N, int K) {
  __shared__ unsigned short sA[3][8192];
  __shared__ unsigned short sB[3][4096];
  const int nbm = M >> 8, nbn = N >> 7;     // 16, 20
  const int CM = nbm >> 2, CN = nbn >> 1;   // 4, 10
  int wg = blockIdx.x;
  const int xcd = wg & 7;
  const int idx = wg >> 3;
  const int bm = (xcd >> 1) * CM + idx / CN;
  const int bn = (xcd & 1) * CN + idx % CN;
  const int tid = threadIdx.x;
  const int lane = tid & 63, wave = tid >> 6;
  const int wr = wave >> 1, wc = wave & 1;
  const int lc = lane & 15, lr = lane >> 4;

  const int sub = (lane & 7) ^ (lane >> 3);
  const int rstage = wave * 16 + ((lane >> 3) << 1) + (sub >> 2);
  const int cstage = (sub & 3) * 8;
  const unsigned short* Agp = A + (size_t)(bm * 256 + rstage) * K + cstage;
  const unsigned short* Bgp = Bt + (size_t)(bn * 128 + rstage) * K + cstage;
  const size_t halfoff = (size_t)128 * K;

  const int loff = ((lc >> 1) << 7) + (((((lc & 1) << 2) | lr) ^ (lc >> 1)) << 4);

  f32x4 acc[4][4];
  const f32x4 zero = {0.f, 0.f, 0.f, 0.f};
#pragma unroll
  for (int m = 0; m < 4; ++m)
#pragma unroll
    for (int n = 0; n < 4; ++n) acc[m][n] = zero;

  auto stage = [&](int buf, int t) {
    gload16(Agp + t * 32, &sA[buf][wave * 512]);
    gload16(Agp + halfoff + t * 32, &sA[buf][4096 + wave * 512]);
    gload16(Bgp + t * 32, &sB[buf][wave * 512]);
  };

  const int NT = K >> 5;   // 80
  stage(0, 0);
  stage(1, 1);
  int b0 = 0;
  for (int t = 0; t < NT; ++t) {
    if (t < NT - 1) asm volatile("s_waitcnt vmcnt(3)" ::: "memory");
    else            asm volatile("s_waitcnt vmcnt(0)" ::: "memory");
    __builtin_amdgcn_s_barrier();
    asm volatile("" ::: "memory");

    const char* bufA = (const char*)&sA[b0][0];
    const char* bufB = (const char*)&sB[b0][0];
    bf16x8 af[4], bfr[4];
#pragma unroll
    for (int mi = 0; mi < 4; ++mi)
      af[mi] = *(const bf16x8*)(bufA + ((wr * 64 + mi * 16) << 6) + loff);
#pragma unroll
    for (int ni = 0; ni < 4; ++ni)
      bfr[ni] = *(const bf16x8*)(bufB + ((wc * 64 + ni * 16) << 6) + loff);

    if (t + 2 < NT) {
      int bs = b0 - 1; if (bs < 0) bs = 2;   // (t+2)%3
      stage(bs, t + 2);
    }

    asm volatile("s_waitcnt lgkmcnt(0)" ::: "memory");
    __builtin_amdgcn_sched_barrier(0);
    __builtin_amdgcn_s_setprio(1);
#pragma unroll
    for (int mi = 0; mi < 4; ++mi)
#pragma unroll
      for (int ni = 0; ni < 4; ++ni)
        acc[mi][ni] = __builtin_amdgcn_mfma_f32_16x16x32_bf16(af[mi], bfr[ni], acc[mi][ni], 0, 0, 0);
    __builtin_amdgcn_s_setprio(0);
    ++b0; if (b0 == 3) b0 = 0;
  }

  __builtin_amdgcn_s_barrier();
  const int rowb = bm * 256 + wr * 64;
  const int colb = bn * 128 + wc * 64;
  float* fw = (float*)&sA[0][0] + wave * 2112;
#pragma unroll
  for (int p2 = 0; p2 < 2; ++p2) {
#pragma unroll
    for (int mfi = 0; mfi < 2; ++mfi) {
      const int mf = p2 * 2 + mfi;
#pragma unroll
      for (int ni = 0; ni < 4; ++ni) {
        const float bv = bias[colb + ni * 16 + lc];
#pragma unroll
        for (int jj = 0; jj < 4; ++jj)
          fw[(mfi * 16 + lr * 4 + jj) * 66 + ni * 16 + lc] = acc[mf][ni][jj] + bv;
      }
    }
    asm volatile("" ::: "memory");
#pragma unroll
    for (int i = 0; i < 8; ++i) {
      const int idx2 = i * 64 + lane;
      const int r = idx2 >> 4, c4 = idx2 & 15;
      *(float4*)&Cf[(size_t)(rowb + p2 * 32 + r) * N + colb + c4 * 4] =
          *(const float4*)&fw[r * 66 + c4 * 4];
    }
    asm volatile("" ::: "memory");
  }
}

// ---------------- RoPE + head split: qkv -> Q (scaled, log2-domain), K, V^T -
// Q scale = 80^-0.5 * log2(e) so attention scores arrive pre-multiplied for
// exp2-domain softmax (saves one v_mul per exp in the attn inner loop).
__global__ __launch_bounds__(256) void k_rope(const unsigned short* __restrict__ qkv,
                                              unsigned short* __restrict__ Qw,
                                              unsigned short* __restrict__ Kw,
                                              unsigned short* __restrict__ Vt) {
  const int blk = blockIdx.x;
  const int sc = blk & 31;
  const int bh = blk >> 5;
  const int b = bh >> 5, h = bh & 31;
  const int s0 = sc * 64;
  __shared__ float cs0[64][16], sn0[64][16];
  __shared__ unsigned short vbuf[64][88];
  const int tid = threadIdx.x;
  for (int i = tid; i < 64 * 16; i += 256) {
    int sl = i >> 4, fi = i & 15;
    float ang = (float)(s0 + sl) * __expf(-(float)fi * 0.575646273248511421f);
    cs0[sl][fi] = cosf(ang);
    sn0[sl][fi] = sinf(ang);
  }
  const size_t row0 = (size_t)(b * S_LEN + s0) * QKV_N;
  for (int i = tid; i < 64 * 10; i += 256) {
    int sl = i / 10, o = i - sl * 10;
    *(u16x8*)&vbuf[sl][o * 8] =
        *(const u16x8*)&qkv[row0 + (size_t)sl * QKV_N + 2 * HIDDEN + h * HD + o * 8];
  }
  __syncthreads();
  const size_t obase = ((size_t)bh * S_LEN + s0) * DPAD;
  const float SCALE = 0.16129838f;   // 80^-0.5 * log2(e)
  for (int i = tid; i < 64 * 12; i += 256) {
    int sl = i / 12, o = i - sl * 12;
    u16x8 outq = {0, 0, 0, 0, 0, 0, 0, 0};
    u16x8 outk = {0, 0, 0, 0, 0, 0, 0, 0};
    if (o < 10) {
      const unsigned short* rp = qkv + row0 + (size_t)sl * QKV_N + h * HD;
      u16x8 xq = *(const u16x8*)(rp + o * 8);
      u16x8 xk = *(const u16x8*)(rp + HIDDEN + o * 8);
      if (o < 2) {
        u16x8 yq = *(const u16x8*)(rp + (o + 2) * 8);
        u16x8 yk = *(const u16x8*)(rp + HIDDEN + (o + 2) * 8);
#pragma unroll
        for (int j = 0; j < 8; ++j) {
          float c = cs0[sl][o * 8 + j], s = sn0[sl][o * 8 + j];
          outq[j] = f2bf((bf2f(xq[j]) * c - bf2f(yq[j]) * s) * SCALE);
          outk[j] = f2bf(bf2f(xk[j]) * c - bf2f(yk[j]) * s);
        }
      } else if (o < 4) {
        u16x8 yq = *(const u16x8*)(rp + (o - 2) * 8);
        u16x8 yk = *(const u16x8*)(rp + HIDDEN + (o - 2) * 8);
#pragma unroll
        for (int j = 0; j < 8; ++j) {
          float c = cs0[sl][(o - 2) * 8 + j], s = sn0[sl][(o - 2) * 8 + j];
          outq[j] = f2bf((bf2f(xq[j]) * c + bf2f(yq[j]) * s) * SCALE);
          outk[j] = f2bf(bf2f(xk[j]) * c + bf2f(yk[j]) * s);
        }
      } else {
#pragma unroll
        for (int j = 0; j < 8; ++j) {
          outq[j] = f2bf(bf2f(xq[j]) * SCALE);
          outk[j] = xk[j];
        }
      }
    }
    *(u16x8*)&Qw[obase + (size_t)sl * DPAD + o * 8] = outq;
    *(u16x8*)&Kw[obase + (size_t)sl * DPAD + o * 8] = outk;
  }
  const size_t vtb = (size_t)bh * DPAD * S_LEN + s0;
  for (int i = tid; i < 80 * 8; i += 256) {
    int d = i >> 3, so = i & 7;
    u16x8 v;
#pragma unroll
    for (int j = 0; j < 8; ++j) v[j] = vbuf[so * 8 + j][d];
    *(u16x8*)&Vt[vtb + (size_t)d * S_LEN + so * 8] = v;
  }
}

// ---------------- flash attention (causal), exp2-domain softmax --------------
// Scores arrive scaled by log2(e): softmax uses exp2f (bare v_exp_f32, no
// per-element mul).  Defer-max threshold 8 nat -> 11.54 log2.
__global__ __launch_bounds__(256, 2) void k_attn(const unsigned short* __restrict__ Qw,
                                                 const unsigned short* __restrict__ Kw,
                                                 const unsigned short* __restrict__ Vt,
                                                 unsigned short* __restrict__ O) {
  __shared__ unsigned short sK[2][64 * 104];
  __shared__ unsigned short sV[2][80 * 72];
  __shared__ unsigned short sP[4][16 * 72];
  const int p = blockIdx.x >> 6;
  const int bh = blockIdx.x & 63;
  const int b = bh >> 5, h = bh & 31;
  const int tid = threadIdx.x;
  const int wave = tid >> 6, lane = tid & 63;
  const int lr = lane >> 4, lc = lane & 15;
  unsigned short* Pw = &sP[wave][0];

  const unsigned short* Kh = Kw + (size_t)bh * S_LEN * DPAD;
  const unsigned short* Vh = Vt + (size_t)bh * DPAD * S_LEN;
  const unsigned short* Qh = Qw + (size_t)bh * S_LEN * DPAD;

  const int kr = tid >> 2, kc = (tid & 3) * 24;
  const int vr = tid >> 3, vc = (tid & 7) * 8;

  u16x8 kst0, kst1, kst2, vst0, vst1, vst2;
  auto gload = [&](int t) {
    const unsigned short* Kg = Kh + ((size_t)(t * 64 + kr)) * DPAD + kc;
    kst0 = *(const u16x8*)(Kg);
    kst1 = *(const u16x8*)(Kg + 8);
    kst2 = *(const u16x8*)(Kg + 16);
    const unsigned short* Vg = Vh + (size_t)vr * S_LEN + t * 64 + vc;
    vst0 = *(const u16x8*)(Vg);
    vst1 = *(const u16x8*)(Vg + 32 * S_LEN);
    if (tid < 128) vst2 = *(const u16x8*)(Vg + (size_t)64 * S_LEN);
  };
  auto swrite = [&](int buf) {
    *(u16x8*)&sK[buf][kr * 104 + kc] = kst0;
    *(u16x8*)&sK[buf][kr * 104 + kc + 8] = kst1;
    *(u16x8*)&sK[buf][kr * 104 + kc + 16] = kst2;
    *(u16x8*)&sV[buf][vr * 72 + vc] = vst0;
    *(u16x8*)&sV[buf][(vr + 32) * 72 + vc] = vst1;
    if (tid < 128) *(u16x8*)&sV[buf][(vr + 64) * 72 + vc] = vst2;
  };

  const f32x4 zero = {0.f, 0.f, 0.f, 0.f};

#pragma unroll 1
  for (int qi = 0; qi < 2; ++qi) {
    const int qt = qi ? (15 - p) : p;
    const int nt = 2 * qt + 2;
    const int wbase = qt * 128 + wave * 32;

    bf16x8 qf[2][3];
#pragma unroll
    for (int m = 0; m < 2; ++m)
#pragma unroll
      for (int ks = 0; ks < 3; ++ks)
        qf[m][ks] = *(const bf16x8*)&Qh[(size_t)(wbase + m * 16 + lc) * DPAD + ks * 32 + lr * 8];

    f32x4 oacc[2][5];
#pragma unroll
    for (int m = 0; m < 2; ++m)
#pragma unroll
      for (int n = 0; n < 5; ++n) oacc[m][n] = zero;
    float mrun[2] = {-1e30f, -1e30f}, lrun[2] = {0.f, 0.f};

    gload(0);
    __syncthreads();
    swrite(0);
    int cur = 0;

#pragma unroll 1
    for (int t = 0; t < nt; ++t) {
      __syncthreads();
      if (t + 1 < nt) gload(t + 1);
      const int ktb = t * 64;
      const bool act0 = ktb <= wbase + 15;
      const bool act1 = ktb <= wbase + 31;
      if (act1) {
        const unsigned short* Kc = sK[cur];
        const unsigned short* Vc = sV[cur];
        f32x4 sf[2][4];
#pragma unroll
        for (int n = 0; n < 4; ++n) {
          sf[0][n] = zero; sf[1][n] = zero;
#pragma unroll
          for (int ks = 0; ks < 3; ++ks) {
            bf16x8 kf = *(const bf16x8*)&Kc[(n * 16 + lc) * 104 + ks * 32 + lr * 8];
            if (act0) sf[0][n] = __builtin_amdgcn_mfma_f32_16x16x32_bf16(kf, qf[0][ks], sf[0][n], 0, 0, 0);
            sf[1][n] = __builtin_amdgcn_mfma_f32_16x16x32_bf16(kf, qf[1][ks], sf[1][n], 0, 0, 0);
          }
        }
        bf16x8 vf[5][2];
#pragma unroll
        for (int n = 0; n < 5; ++n)
#pragma unroll
          for (int ks = 0; ks < 2; ++ks)
            vf[n][ks] = *(const bf16x8*)&Vc[(n * 16 + lc) * 72 + ks * 32 + lr * 8];
#pragma unroll
        for (int m = 0; m < 2; ++m) {
          if (m == 0 && !act0) continue;
          const int qrow0 = wbase + m * 16;
          if (ktb + 63 > qrow0) {
#pragma unroll
            for (int n = 0; n < 4; ++n)
#pragma unroll
              for (int j = 0; j < 4; ++j)
                if (ktb + n * 16 + lr * 4 + j > qrow0 + lc) sf[m][n][j] = -1e30f;
          }
          float t0 = sf[m][0][0];
#pragma unroll
          for (int n = 0; n < 4; ++n)
#pragma unroll
            for (int j = 0; j < 4; ++j) t0 = fmaxf(t0, sf[m][n][j]);
          t0 = fmaxf(t0, __shfl_xor(t0, 16));
          t0 = fmaxf(t0, __shfl_xor(t0, 32));
          const bool need = __any(t0 > mrun[m] + 11.54f);   // 8 nat in log2
          const float nm = need ? fmaxf(mrun[m], t0) : mrun[m];
          float ps = 0.f;
#pragma unroll
          for (int n = 0; n < 4; ++n)
#pragma unroll
            for (int j = 0; j < 4; ++j) {
              float e = exp2f(sf[m][n][j] - nm);
              sf[m][n][j] = e;
              ps += e;
            }
          ps += __shfl_xor(ps, 16);
          ps += __shfl_xor(ps, 32);
          if (need) {
            const float corrq = exp2f(mrun[m] - nm);
            mrun[m] = nm;
            lrun[m] = lrun[m] * corrq + ps;
            float cj[4];
#pragma unroll
            for (int j = 0; j < 4; ++j) cj[j] = __shfl(corrq, lr * 4 + j, 16);
#pragma unroll
            for (int n = 0; n < 5; ++n)
#pragma unroll
              for (int j = 0; j < 4; ++j) oacc[m][n][j] *= cj[j];
          } else {
            lrun[m] += ps;
          }
#pragma unroll
          for (int n = 0; n < 4; ++n) {
            unsigned lo = (unsigned)f2bf(sf[m][n][0]) | ((unsigned)f2bf(sf[m][n][1]) << 16);
            unsigned hi = (unsigned)f2bf(sf[m][n][2]) | ((unsigned)f2bf(sf[m][n][3]) << 16);
            uint2 u; u.x = lo; u.y = hi;
            *(uint2*)&Pw[lc * 72 + n * 16 + lr * 4] = u;
          }
          asm volatile("" ::: "memory");
          bf16x8 pa0 = *(const bf16x8*)&Pw[lc * 72 + lr * 8];
          bf16x8 pa1 = *(const bf16x8*)&Pw[lc * 72 + 32 + lr * 8];
#pragma unroll
          for (int n = 0; n < 5; ++n) {
            oacc[m][n] = __builtin_amdgcn_mfma_f32_16x16x32_bf16(pa0, vf[n][0], oacc[m][n], 0, 0, 0);
            oacc[m][n] = __builtin_amdgcn_mfma_f32_16x16x32_bf16(pa1, vf[n][1], oacc[m][n], 0, 0, 0);
          }
          asm volatile("" ::: "memory");
        }
      }
      if (t + 1 < nt) swrite(cur ^ 1);
      cur ^= 1;
    }

#pragma unroll
    for (int m = 0; m < 2; ++m) {
      float linv[4];
#pragma unroll
      for (int j = 0; j < 4; ++j) {
        float lj = __shfl(lrun[m], lr * 4 + j, 16);
        linv[j] = 1.f / lj;
      }
      const int q0 = wbase + m * 16 + lr * 4;
#pragma unroll
      for (int n = 0; n < 5; ++n) {
        const int d = n * 16 + lc;
#pragma unroll
        for (int j = 0; j < 4; ++j)
          O[((size_t)(b * S_LEN) + q0 + j) * HIDDEN + h * HD + d] = f2bf(oacc[m][n][j] * linv[j]);
      }
    }
  }
}

extern "C" void kernel_launch(void* const* d_in, const int* in_sizes, int n_in,
                              void* d_out, int out_size, void* d_ws, size_t ws_size,
                              hipStream_t stream) {
  (void)in_sizes; (void)n_in; (void)out_size; (void)ws_size;
  const float* hidden  = (const float*)d_in[1];
  const float* w_qkv   = (const float*)d_in[2];
  const float* b_qkv   = (const float*)d_in[3];
  const float* w_dense = (const float*)d_in[4];
  const float* b_dense = (const float*)d_in[5];
  char* ws = (char*)d_ws;
  unsigned short* Abf   = (unsigned short*)(ws + 0);          // 4096x2560 bf16
  unsigned short* Wqkvt = (unsigned short*)(ws + 20971520);   // 7680x2560 bf16
  unsigned short* Wdt   = (unsigned short*)(ws + 60293120);   // 2560x2560 bf16
  unsigned short* QKVb  = (unsigned short*)(ws + 73400320);   // 4096x7680 bf16
  unsigned short* Qw    = (unsigned short*)(ws + 136314880);  // 64x2048x96 bf16
  unsigned short* Kw    = (unsigned short*)(ws + 161480704);
  unsigned short* Vt    = (unsigned short*)(ws + 186646528);
  unsigned short* Obf   = (unsigned short*)(ws + 211812352);  // 4096x2560 bf16

  k_prep<<<16640, 256, 0, stream>>>(hidden, Abf, w_qkv, Wqkvt, w_dense, Wdt);
  k_gemm_qkv<<<480, 512, 0, stream>>>(Abf, Wqkvt, b_qkv, QKVb, 4096, 7680, 2560);
  k_rope<<<2048, 256, 0, stream>>>(QKVb, Qw, Kw, Vt);
  k_attn<<<512, 256, 0, stream>>>(Qw, Kw, Vt, Obf);
  k_gemm_out<<<320, 512, 0, stream>>>(Obf, Wdt, b_dense, (float*)d_out, 4096, 2560, 2560);
}

// Round 19
// 389.748 us; speedup vs baseline: 1.0305x; 1.0305x over previous
//
#include <hip/hip_runtime.h>

#define S_LEN 2048
#define NHEAD 32
#define HD 80
#define DPAD 96
#define HIDDEN 2560
#define QKV_N 7680

typedef __attribute__((ext_vector_type(8))) short bf16x8;
typedef __attribute__((ext_vector_type(8))) unsigned short u16x8;
typedef __attribute__((ext_vector_type(4))) float f32x4;

__device__ __forceinline__ unsigned short f2bf(float f) {
  unsigned int u = __float_as_uint(f);
  u += 0x7fffu + ((u >> 16) & 1u);   // RNE
  return (unsigned short)(u >> 16);
}
__device__ __forceinline__ float bf2f(unsigned short h) {
  return __uint_as_float(((unsigned int)h) << 16);
}

__device__ __forceinline__ void gload16(const void* g, void* l) {
  __builtin_amdgcn_global_load_lds((const __attribute__((address_space(1))) void*)g,
                                   (__attribute__((address_space(3))) void*)l, 16, 0, 0);
}

// ---------------- fused prep: fp32->bf16 cvt + both weight transposes -------
__global__ __launch_bounds__(256) void k_prep(const float* __restrict__ hidden,
                                              unsigned short* __restrict__ Abf,
                                              const float* __restrict__ w_qkv,
                                              unsigned short* __restrict__ Wqkvt,
                                              const float* __restrict__ w_dense,
                                              unsigned short* __restrict__ Wdt) {
  __shared__ float tile[64][68];
  const int blk = blockIdx.x;
  if (blk < 10240) {
    int i = blk * 256 + threadIdx.x;
    float4 v = reinterpret_cast<const float4*>(hidden)[i];
    ushort4 o;
    o.x = f2bf(v.x); o.y = f2bf(v.y); o.z = f2bf(v.z); o.w = f2bf(v.w);
    reinterpret_cast<ushort4*>(Abf)[i] = o;
    return;
  }
  const float* in;
  unsigned short* out;
  int R, C, tc, tr;
  if (blk < 15040) {
    int t = blk - 10240;
    in = w_qkv; out = Wqkvt; R = 2560; C = 7680;
    tc = (t % 120) * 64; tr = (t / 120) * 64;
  } else {
    int t = blk - 15040;
    in = w_dense; out = Wdt; R = 2560; C = 2560;
    tc = (t % 40) * 64; tr = (t / 40) * 64;
  }
  for (int i = threadIdx.x; i < 64 * 16; i += 256) {
    int r = i >> 4, c4 = i & 15;
    float4 v = *(const float4*)&in[(size_t)(tr + r) * C + tc + c4 * 4];
    *(float4*)&tile[r][c4 * 4] = v;
  }
  __syncthreads();
  for (int i = threadIdx.x; i < 8 * 64; i += 256) {
    int ro = i >> 6, c = i & 63;
    u16x8 v;
#pragma unroll
    for (int j = 0; j < 8; ++j) v[j] = f2bf(tile[ro * 8 + j][c]);
    *(u16x8*)&out[(size_t)(tc + c) * R + tr + ro * 8] = v;
  }
}

// ---------------- gemm1 (QKV): 256x256, BK=32, R15-exact ---------------------
__global__ __launch_bounds__(512, 2)
void k_gemm_qkv(const unsigned short* __restrict__ A,
                const unsigned short* __restrict__ Bt,
                const float* __restrict__ bias,
                unsigned short* __restrict__ Cbf,
                int M, int N, int K) {
  __shared__ unsigned short sA[4][8192];
  __shared__ unsigned short sB[4][8192];
  const int nbm = M >> 8, nbn = N >> 8;
  const int CM = nbm >> 2, CN = nbn >> 1;
  int wg = blockIdx.x;
  const int xcd = wg & 7;
  const int idx = wg >> 3;
  const int bm = (xcd >> 1) * CM + idx / CN;
  const int bn = (xcd & 1) * CN + idx % CN;
  const int tid = threadIdx.x;
  const int lane = tid & 63, wave = tid >> 6;
  const int wr = wave >> 2, wc = wave & 3;
  const int lc = lane & 15, lr = lane >> 4;

  const int sub = (lane & 7) ^ (lane >> 3);
  const int rstage = wave * 16 + ((lane >> 3) << 1) + (sub >> 2);
  const int cstage = (sub & 3) * 8;
  const unsigned short* Agp = A + (size_t)(bm * 256 + rstage) * K + cstage;
  const unsigned short* Bgp = Bt + (size_t)(bn * 256 + rstage) * K + cstage;
  const size_t halfoff = (size_t)128 * K;

  const int loff = ((lc >> 1) << 7) + (((((lc & 1) << 2) | lr) ^ (lc >> 1)) << 4);

  f32x4 acc[8][4];
  const f32x4 zero = {0.f, 0.f, 0.f, 0.f};
#pragma unroll
  for (int m = 0; m < 8; ++m)
#pragma unroll
    for (int n = 0; n < 4; ++n) acc[m][n] = zero;

  auto stage = [&](int buf, int t) {
    gload16(Agp + t * 32, &sA[buf][wave * 512]);
    gload16(Agp + halfoff + t * 32, &sA[buf][4096 + wave * 512]);
    gload16(Bgp + t * 32, &sB[buf][wave * 512]);
    gload16(Bgp + halfoff + t * 32, &sB[buf][4096 + wave * 512]);
  };

  const int NT = K >> 5;   // 80
#pragma unroll
  for (int t = 0; t < 3; ++t) stage(t, t);

  const int nj = NT >> 2;
  for (int j = 0; j < nj; ++j) {
#pragma unroll
    for (int to = 0; to < 4; ++to) {
      const int t = (j << 2) + to;
      if (t < NT - 2)       asm volatile("s_waitcnt vmcnt(8)" ::: "memory");
      else if (t == NT - 2) asm volatile("s_waitcnt vmcnt(4)" ::: "memory");
      else                  asm volatile("s_waitcnt vmcnt(0)" ::: "memory");
      __builtin_amdgcn_s_barrier();
      asm volatile("" ::: "memory");

      const char* bufA = (const char*)&sA[to][0];
      const char* bufB = (const char*)&sB[to][0];
      bf16x8 af[8], bfr[4];
#pragma unroll
      for (int mi = 0; mi < 8; ++mi)
        af[mi] = *(const bf16x8*)(bufA + ((wr * 128 + mi * 16) << 6) + loff);
#pragma unroll
      for (int ni = 0; ni < 4; ++ni)
        bfr[ni] = *(const bf16x8*)(bufB + ((wc * 64 + ni * 16) << 6) + loff);

      if (t + 3 < NT) stage((to + 3) & 3, t + 3);

      asm volatile("s_waitcnt lgkmcnt(0)" ::: "memory");
      __builtin_amdgcn_sched_barrier(0);
      __builtin_amdgcn_s_setprio(1);
#pragma unroll
      for (int mi = 0; mi < 8; ++mi)
#pragma unroll
        for (int ni = 0; ni < 4; ++ni)
          acc[mi][ni] = __builtin_amdgcn_mfma_f32_16x16x32_bf16(af[mi], bfr[ni], acc[mi][ni], 0, 0, 0);
      __builtin_amdgcn_s_setprio(0);
    }
  }

  __builtin_amdgcn_s_barrier();
  const int rowb = bm * 256 + wr * 128;
  const int colb = bn * 256 + wc * 64;
  unsigned short* myl = (wave < 4) ? &sA[wave][0] : &sB[wave - 4][0];
#pragma unroll
  for (int ni = 0; ni < 4; ++ni) {
    const float bv = bias[colb + ni * 16 + lc];
#pragma unroll
    for (int mf = 0; mf < 8; ++mf)
#pragma unroll
      for (int jj = 0; jj < 4; ++jj)
        myl[(mf * 16 + lr * 4 + jj) * 64 + ni * 16 + lc] = f2bf(acc[mf][ni][jj] + bv);
  }
  asm volatile("" ::: "memory");
#pragma unroll
  for (int i = 0; i < 16; ++i) {
    const int idx2 = i * 64 + lane;
    const int r = idx2 >> 3, c = idx2 & 7;
    *(u16x8*)&Cbf[(size_t)(rowb + r) * N + colb + c * 8] = *(const u16x8*)&myl[r * 64 + c * 8];
  }
}

// ---------------- gemm2 (out-proj): 256x128 tile, 8 waves, 3-deep -----------
__global__ __launch_bounds__(512, 2)
void k_gemm_out(const unsigned short* __restrict__ A,
                const unsigned short* __restrict__ Bt,
                const float* __restrict__ bias,
                float* __restrict__ Cf,
                int M, int N, int K) {
  __shared__ unsigned short sA[3][8192];
  __shared__ unsigned short sB[3][4096];
  const int nbm = M >> 8, nbn = N >> 7;     // 16, 20
  const int CM = nbm >> 2, CN = nbn >> 1;   // 4, 10
  int wg = blockIdx.x;
  const int xcd = wg & 7;
  const int idx = wg >> 3;
  const int bm = (xcd >> 1) * CM + idx / CN;
  const int bn = (xcd & 1) * CN + idx % CN;
  const int tid = threadIdx.x;
  const int lane = tid & 63, wave = tid >> 6;
  const int wr = wave >> 1, wc = wave & 1;
  const int lc = lane & 15, lr = lane >> 4;

  const int sub = (lane & 7) ^ (lane >> 3);
  const int rstage = wave * 16 + ((lane >> 3) << 1) + (sub >> 2);
  const int cstage = (sub & 3) * 8;
  const unsigned short* Agp = A + (size_t)(bm * 256 + rstage) * K + cstage;
  const unsigned short* Bgp = Bt + (size_t)(bn * 128 + rstage) * K + cstage;
  const size_t halfoff = (size_t)128 * K;

  const int loff = ((lc >> 1) << 7) + (((((lc & 1) << 2) | lr) ^ (lc >> 1)) << 4);

  f32x4 acc[4][4];
  const f32x4 zero = {0.f, 0.f, 0.f, 0.f};
#pragma unroll
  for (int m = 0; m < 4; ++m)
#pragma unroll
    for (int n = 0; n < 4; ++n) acc[m][n] = zero;

  auto stage = [&](int buf, int t) {
    gload16(Agp + t * 32, &sA[buf][wave * 512]);
    gload16(Agp + halfoff + t * 32, &sA[buf][4096 + wave * 512]);
    gload16(Bgp + t * 32, &sB[buf][wave * 512]);
  };

  const int NT = K >> 5;   // 80
  stage(0, 0);
  stage(1, 1);
  int b0 = 0;
  for (int t = 0; t < NT; ++t) {
    if (t < NT - 1) asm volatile("s_waitcnt vmcnt(3)" ::: "memory");
    else            asm volatile("s_waitcnt vmcnt(0)" ::: "memory");
    __builtin_amdgcn_s_barrier();
    asm volatile("" ::: "memory");

    const char* bufA = (const char*)&sA[b0][0];
    const char* bufB = (const char*)&sB[b0][0];
    bf16x8 af[4], bfr[4];
#pragma unroll
    for (int mi = 0; mi < 4; ++mi)
      af[mi] = *(const bf16x8*)(bufA + ((wr * 64 + mi * 16) << 6) + loff);
#pragma unroll
    for (int ni = 0; ni < 4; ++ni)
      bfr[ni] = *(const bf16x8*)(bufB + ((wc * 64 + ni * 16) << 6) + loff);

    if (t + 2 < NT) {
      int bs = b0 - 1; if (bs < 0) bs = 2;   // (t+2)%3
      stage(bs, t + 2);
    }

    asm volatile("s_waitcnt lgkmcnt(0)" ::: "memory");
    __builtin_amdgcn_sched_barrier(0);
    __builtin_amdgcn_s_setprio(1);
#pragma unroll
    for (int mi = 0; mi < 4; ++mi)
#pragma unroll
      for (int ni = 0; ni < 4; ++ni)
        acc[mi][ni] = __builtin_amdgcn_mfma_f32_16x16x32_bf16(af[mi], bfr[ni], acc[mi][ni], 0, 0, 0);
    __builtin_amdgcn_s_setprio(0);
    ++b0; if (b0 == 3) b0 = 0;
  }

  __builtin_amdgcn_s_barrier();
  const int rowb = bm * 256 + wr * 64;
  const int colb = bn * 128 + wc * 64;
  float* fw = (float*)&sA[0][0] + wave * 2112;
#pragma unroll
  for (int p2 = 0; p2 < 2; ++p2) {
#pragma unroll
    for (int mfi = 0; mfi < 2; ++mfi) {
      const int mf = p2 * 2 + mfi;
#pragma unroll
      for (int ni = 0; ni < 4; ++ni) {
        const float bv = bias[colb + ni * 16 + lc];
#pragma unroll
        for (int jj = 0; jj < 4; ++jj)
          fw[(mfi * 16 + lr * 4 + jj) * 66 + ni * 16 + lc] = acc[mf][ni][jj] + bv;
      }
    }
    asm volatile("" ::: "memory");
#pragma unroll
    for (int i = 0; i < 8; ++i) {
      const int idx2 = i * 64 + lane;
      const int r = idx2 >> 4, c4 = idx2 & 15;
      *(float4*)&Cf[(size_t)(rowb + p2 * 32 + r) * N + colb + c4 * 4] =
          *(const float4*)&fw[r * 66 + c4 * 4];
    }
    asm volatile("" ::: "memory");
  }
}

// ---------------- RoPE + head split: qkv -> Q (scaled), K, V^T --------------
__global__ __launch_bounds__(256) void k_rope(const unsigned short* __restrict__ qkv,
                                              unsigned short* __restrict__ Qw,
                                              unsigned short* __restrict__ Kw,
                                              unsigned short* __restrict__ Vt) {
  const int blk = blockIdx.x;
  const int sc = blk & 31;
  const int bh = blk >> 5;
  const int b = bh >> 5, h = bh & 31;
  const int s0 = sc * 64;
  __shared__ float cs0[64][16], sn0[64][16];
  __shared__ unsigned short vbuf[64][88];
  const int tid = threadIdx.x;
  for (int i = tid; i < 64 * 16; i += 256) {
    int sl = i >> 4, fi = i & 15;
    float ang = (float)(s0 + sl) * __expf(-(float)fi * 0.575646273248511421f);
    cs0[sl][fi] = cosf(ang);
    sn0[sl][fi] = sinf(ang);
  }
  const size_t row0 = (size_t)(b * S_LEN + s0) * QKV_N;
  for (int i = tid; i < 64 * 10; i += 256) {
    int sl = i / 10, o = i - sl * 10;
    *(u16x8*)&vbuf[sl][o * 8] =
        *(const u16x8*)&qkv[row0 + (size_t)sl * QKV_N + 2 * HIDDEN + h * HD + o * 8];
  }
  __syncthreads();
  const size_t obase = ((size_t)bh * S_LEN + s0) * DPAD;
  const float SCALE = 0.111803398874989485f;  // 80^-0.5
  for (int i = tid; i < 64 * 12; i += 256) {
    int sl = i / 12, o = i - sl * 12;
    u16x8 outq = {0, 0, 0, 0, 0, 0, 0, 0};
    u16x8 outk = {0, 0, 0, 0, 0, 0, 0, 0};
    if (o < 10) {
      const unsigned short* rp = qkv + row0 + (size_t)sl * QKV_N + h * HD;
      u16x8 xq = *(const u16x8*)(rp + o * 8);
      u16x8 xk = *(const u16x8*)(rp + HIDDEN + o * 8);
      if (o < 2) {
        u16x8 yq = *(const u16x8*)(rp + (o + 2) * 8);
        u16x8 yk = *(const u16x8*)(rp + HIDDEN + (o + 2) * 8);
#pragma unroll
        for (int j = 0; j < 8; ++j) {
          float c = cs0[sl][o * 8 + j], s = sn0[sl][o * 8 + j];
          outq[j] = f2bf((bf2f(xq[j]) * c - bf2f(yq[j]) * s) * SCALE);
          outk[j] = f2bf(bf2f(xk[j]) * c - bf2f(yk[j]) * s);
        }
      } else if (o < 4) {
        u16x8 yq = *(const u16x8*)(rp + (o - 2) * 8);
        u16x8 yk = *(const u16x8*)(rp + HIDDEN + (o - 2) * 8);
#pragma unroll
        for (int j = 0; j < 8; ++j) {
          float c = cs0[sl][(o - 2) * 8 + j], s = sn0[sl][(o - 2) * 8 + j];
          outq[j] = f2bf((bf2f(xq[j]) * c + bf2f(yq[j]) * s) * SCALE);
          outk[j] = f2bf(bf2f(xk[j]) * c + bf2f(yk[j]) * s);
        }
      } else {
#pragma unroll
        for (int j = 0; j < 8; ++j) {
          outq[j] = f2bf(bf2f(xq[j]) * SCALE);
          outk[j] = xk[j];
        }
      }
    }
    *(u16x8*)&Qw[obase + (size_t)sl * DPAD + o * 8] = outq;
    *(u16x8*)&Kw[obase + (size_t)sl * DPAD + o * 8] = outk;
  }
  const size_t vtb = (size_t)bh * DPAD * S_LEN + s0;
  for (int i = tid; i < 80 * 8; i += 256) {
    int d = i >> 3, so = i & 7;
    u16x8 v;
#pragma unroll
    for (int j = 0; j < 8; ++j) v[j] = vbuf[so * 8 + j][d];
    *(u16x8*)&Vt[vtb + (size_t)d * S_LEN + so * 8] = v;
  }
}

// ---------------- flash attention (causal), R15/R17-exact --------------------
__global__ __launch_bounds__(256, 2) void k_attn(const unsigned short* __restrict__ Qw,
                                                 const unsigned short* __restrict__ Kw,
                                                 const unsigned short* __restrict__ Vt,
                                                 unsigned short* __restrict__ O) {
  __shared__ unsigned short sK[2][64 * 104];
  __shared__ unsigned short sV[2][80 * 72];
  __shared__ unsigned short sP[4][16 * 72];
  const int p = blockIdx.x >> 6;
  const int bh = blockIdx.x & 63;
  const int b = bh >> 5, h = bh & 31;
  const int tid = threadIdx.x;
  const int wave = tid >> 6, lane = tid & 63;
  const int lr = lane >> 4, lc = lane & 15;
  unsigned short* Pw = &sP[wave][0];

  const unsigned short* Kh = Kw + (size_t)bh * S_LEN * DPAD;
  const unsigned short* Vh = Vt + (size_t)bh * DPAD * S_LEN;
  const unsigned short* Qh = Qw + (size_t)bh * S_LEN * DPAD;

  const int kr = tid >> 2, kc = (tid & 3) * 24;
  const int vr = tid >> 3, vc = (tid & 7) * 8;

  u16x8 kst0, kst1, kst2, vst0, vst1, vst2;
  auto gload = [&](int t) {
    const unsigned short* Kg = Kh + ((size_t)(t * 64 + kr)) * DPAD + kc;
    kst0 = *(const u16x8*)(Kg);
    kst1 = *(const u16x8*)(Kg + 8);
    kst2 = *(const u16x8*)(Kg + 16);
    const unsigned short* Vg = Vh + (size_t)vr * S_LEN + t * 64 + vc;
    vst0 = *(const u16x8*)(Vg);
    vst1 = *(const u16x8*)(Vg + 32 * S_LEN);
    if (tid < 128) vst2 = *(const u16x8*)(Vg + (size_t)64 * S_LEN);
  };
  auto swrite = [&](int buf) {
    *(u16x8*)&sK[buf][kr * 104 + kc] = kst0;
    *(u16x8*)&sK[buf][kr * 104 + kc + 8] = kst1;
    *(u16x8*)&sK[buf][kr * 104 + kc + 16] = kst2;
    *(u16x8*)&sV[buf][vr * 72 + vc] = vst0;
    *(u16x8*)&sV[buf][(vr + 32) * 72 + vc] = vst1;
    if (tid < 128) *(u16x8*)&sV[buf][(vr + 64) * 72 + vc] = vst2;
  };

  const f32x4 zero = {0.f, 0.f, 0.f, 0.f};

#pragma unroll 1
  for (int qi = 0; qi < 2; ++qi) {
    const int qt = qi ? (15 - p) : p;
    const int nt = 2 * qt + 2;
    const int wbase = qt * 128 + wave * 32;

    bf16x8 qf[2][3];
#pragma unroll
    for (int m = 0; m < 2; ++m)
#pragma unroll
      for (int ks = 0; ks < 3; ++ks)
        qf[m][ks] = *(const bf16x8*)&Qh[(size_t)(wbase + m * 16 + lc) * DPAD + ks * 32 + lr * 8];

    f32x4 oacc[2][5];
#pragma unroll
    for (int m = 0; m < 2; ++m)
#pragma unroll
      for (int n = 0; n < 5; ++n) oacc[m][n] = zero;
    float mrun[2] = {-1e30f, -1e30f}, lrun[2] = {0.f, 0.f};

    gload(0);
    __syncthreads();
    swrite(0);
    int cur = 0;

#pragma unroll 1
    for (int t = 0; t < nt; ++t) {
      __syncthreads();
      if (t + 1 < nt) gload(t + 1);
      const int ktb = t * 64;
      const bool act0 = ktb <= wbase + 15;
      const bool act1 = ktb <= wbase + 31;
      if (act1) {
        const unsigned short* Kc = sK[cur];
        const unsigned short* Vc = sV[cur];
        f32x4 sf[2][4];
#pragma unroll
        for (int n = 0; n < 4; ++n) {
          sf[0][n] = zero; sf[1][n] = zero;
#pragma unroll
          for (int ks = 0; ks < 3; ++ks) {
            bf16x8 kf = *(const bf16x8*)&Kc[(n * 16 + lc) * 104 + ks * 32 + lr * 8];
            if (act0) sf[0][n] = __builtin_amdgcn_mfma_f32_16x16x32_bf16(kf, qf[0][ks], sf[0][n], 0, 0, 0);
            sf[1][n] = __builtin_amdgcn_mfma_f32_16x16x32_bf16(kf, qf[1][ks], sf[1][n], 0, 0, 0);
          }
        }
        bf16x8 vf[5][2];
#pragma unroll
        for (int n = 0; n < 5; ++n)
#pragma unroll
          for (int ks = 0; ks < 2; ++ks)
            vf[n][ks] = *(const bf16x8*)&Vc[(n * 16 + lc) * 72 + ks * 32 + lr * 8];
#pragma unroll
        for (int m = 0; m < 2; ++m) {
          if (m == 0 && !act0) continue;
          const int qrow0 = wbase + m * 16;
          if (ktb + 63 > qrow0) {
#pragma unroll
            for (int n = 0; n < 4; ++n)
#pragma unroll
              for (int j = 0; j < 4; ++j)
                if (ktb + n * 16 + lr * 4 + j > qrow0 + lc) sf[m][n][j] = -1e30f;
          }
          float t0 = sf[m][0][0];
#pragma unroll
          for (int n = 0; n < 4; ++n)
#pragma unroll
            for (int j = 0; j < 4; ++j) t0 = fmaxf(t0, sf[m][n][j]);
          t0 = fmaxf(t0, __shfl_xor(t0, 16));
          t0 = fmaxf(t0, __shfl_xor(t0, 32));
          const bool need = __any(t0 > mrun[m] + 8.f);
          const float nm = need ? fmaxf(mrun[m], t0) : mrun[m];
          float ps = 0.f;
#pragma unroll
          for (int n = 0; n < 4; ++n)
#pragma unroll
            for (int j = 0; j < 4; ++j) {
              float e = __expf(sf[m][n][j] - nm);
              sf[m][n][j] = e;
              ps += e;
            }
          ps += __shfl_xor(ps, 16);
          ps += __shfl_xor(ps, 32);
          if (need) {
            const float corrq = __expf(mrun[m] - nm);
            mrun[m] = nm;
            lrun[m] = lrun[m] * corrq + ps;
            float cj[4];
#pragma unroll
            for (int j = 0; j < 4; ++j) cj[j] = __shfl(corrq, lr * 4 + j, 16);
#pragma unroll
            for (int n = 0; n < 5; ++n)
#pragma unroll
              for (int j = 0; j < 4; ++j) oacc[m][n][j] *= cj[j];
          } else {
            lrun[m] += ps;
          }
#pragma unroll
          for (int n = 0; n < 4; ++n) {
            unsigned lo = (unsigned)f2bf(sf[m][n][0]) | ((unsigned)f2bf(sf[m][n][1]) << 16);
            unsigned hi = (unsigned)f2bf(sf[m][n][2]) | ((unsigned)f2bf(sf[m][n][3]) << 16);
            uint2 u; u.x = lo; u.y = hi;
            *(uint2*)&Pw[lc * 72 + n * 16 + lr * 4] = u;
          }
          asm volatile("" ::: "memory");
          bf16x8 pa0 = *(const bf16x8*)&Pw[lc * 72 + lr * 8];
          bf16x8 pa1 = *(const bf16x8*)&Pw[lc * 72 + 32 + lr * 8];
#pragma unroll
          for (int n = 0; n < 5; ++n) {
            oacc[m][n] = __builtin_amdgcn_mfma_f32_16x16x32_bf16(pa0, vf[n][0], oacc[m][n], 0, 0, 0);
            oacc[m][n] = __builtin_amdgcn_mfma_f32_16x16x32_bf16(pa1, vf[n][1], oacc[m][n], 0, 0, 0);
          }
          asm volatile("" ::: "memory");
        }
      }
      if (t + 1 < nt) swrite(cur ^ 1);
      cur ^= 1;
    }

#pragma unroll
    for (int m = 0; m < 2; ++m) {
      float linv[4];
#pragma unroll
      for (int j = 0; j < 4; ++j) {
        float lj = __shfl(lrun[m], lr * 4 + j, 16);
        linv[j] = 1.f / lj;
      }
      const int q0 = wbase + m * 16 + lr * 4;
#pragma unroll
      for (int n = 0; n < 5; ++n) {
        const int d = n * 16 + lc;
#pragma unroll
        for (int j = 0; j < 4; ++j)
          O[((size_t)(b * S_LEN) + q0 + j) * HIDDEN + h * HD + d] = f2bf(oacc[m][n][j] * linv[j]);
      }
    }
  }
}

extern "C" void kernel_launch(void* const* d_in, const int* in_sizes, int n_in,
                              void* d_out, int out_size, void* d_ws, size_t ws_size,
                              hipStream_t stream) {
  (void)in_sizes; (void)n_in; (void)out_size; (void)ws_size;
  const float* hidden  = (const float*)d_in[1];
  const float* w_qkv   = (const float*)d_in[2];
  const float* b_qkv   = (const float*)d_in[3];
  const float* w_dense = (const float*)d_in[4];
  const float* b_dense = (const float*)d_in[5];
  char* ws = (char*)d_ws;
  unsigned short* Abf   = (unsigned short*)(ws + 0);          // 4096x2560 bf16
  unsigned short* Wqkvt = (unsigned short*)(ws + 20971520);   // 7680x2560 bf16
  unsigned short* Wdt   = (unsigned short*)(ws + 60293120);   // 2560x2560 bf16
  unsigned short* QKVb  = (unsigned short*)(ws + 73400320);   // 4096x7680 bf16
  unsigned short* Qw    = (unsigned short*)(ws + 136314880);  // 64x2048x96 bf16
  unsigned short* Kw    = (unsigned short*)(ws + 161480704);
  unsigned short* Vt    = (unsigned short*)(ws + 186646528);
  unsigned short* Obf   = (unsigned short*)(ws + 211812352);  // 4096x2560 bf16

  k_prep<<<16640, 256, 0, stream>>>(hidden, Abf, w_qkv, Wqkvt, w_dense, Wdt);
  k_gemm_qkv<<<480, 512, 0, stream>>>(Abf, Wqkvt, b_qkv, QKVb, 4096, 7680, 2560);
  k_rope<<<2048, 256, 0, stream>>>(QKVb, Qw, Kw, Vt);
  k_attn<<<512, 256, 0, stream>>>(Qw, Kw, Vt, Obf);
  k_gemm_out<<<320, 512, 0, stream>>>(Obf, Wdt, b_dense, (float*)d_out, 4096, 2560, 2560);
}